// Round 11
// baseline (295.759 us; speedup 1.0000x reference)
//
#include <hip/hip_runtime.h>

#define NORIENT 8

// XCD-aware block swizzle: dispatch d -> XCD d%8 (round-robin). Remap so each
// XCD gets a contiguous chunk of logical tiles (halo rows shared in its L2).
__device__ __forceinline__ unsigned xcd_swz(unsigned bid, unsigned nwg) {
    unsigned chunk = nwg >> 3;
    return (nwg & 7u) ? bid : (bid & 7u) * chunk + (bid >> 3);
}

// ---------------- forward (LDS-tiled): stride-2 5x5 conv, 1 -> 8 ch ----------------
// Block = 256 threads = 16x16; output tile 32x32 (each thread 2x2 outputs, 8 ch).
// Stage: batched prefetch (R9).
// Weights: R11 — staged into LDS tap-major [ij][c] once per block; each tap
// fetched via two wave-uniform ds_read_b128 (broadcast, conflict-free). Removes
// ALL scalar/global loads from the FMA body (R9/R10 lesson: 200 scattered
// in-body s_loads serialize against ds_reads on shared lgkmcnt; SMEM-pointer
// tap-major made it worse).
__global__ void fwd_conv_lds_kernel(const float* __restrict__ in, long in_img_stride,
                                    const float* __restrict__ filt,   // [8][5][5] original
                                    float* __restrict__ out,
                                    int H, int W, int OH, int OW, int N) {
    constexpr int SROW = 68;                 // LDS row stride (floats), mult of 4
    constexpr int TELEM = 67 * SROW;         // 4556
    __shared__ float tile[TELEM];
    __shared__ float wLds[25 * NORIENT];     // tap-major [ij][c], 800 B

    int nbx = OW >> 5, nby = OH >> 5;
    unsigned sb = xcd_swz(blockIdx.x, gridDim.x);
    int bx = (int)(sb % nbx);
    unsigned t = sb / nbx;
    int by = (int)(t % nby);
    int n = (int)(t / nby);

    const float* __restrict__ ip = in + (long)n * in_img_stride;
    int gy0 = 64 * by - 2, gx0 = 64 * bx - 2;
    int tid = threadIdx.x;

    // ---- stage weights tap-major (once per block) ----
    if (tid < 25 * NORIENT) {
        int ij = tid >> 3, c = tid & 7;      // wLds[ij*8+c] = filt[c][ij]
        wLds[tid] = filt[c * 25 + ij];
    }

    // ---- stage 67x68 input tile: batched prefetch (18 loads in flight) ----
    float v[18];
    unsigned mvalid = 0;
#pragma unroll
    for (int k = 0; k < 18; ++k) {
        int e = tid + k * 256;
        int row = e / SROW, col = e - row * SROW;
        int gy = gy0 + row, gx = gx0 + col;
        bool valid = (e < TELEM) & (gy >= 0) & (gy < H) & (gx >= 0) & (gx < W);
        long a = valid ? ((long)gy * W + gx) : 0;
        v[k] = ip[a];                        // no consumer here -> loads cluster
        mvalid |= (valid ? 1u : 0u) << k;
    }
#pragma unroll
    for (int k = 0; k < 18; ++k) {
        int e = tid + k * 256;
        if (e < TELEM) tile[e] = ((mvalid >> k) & 1u) ? v[k] : 0.f;
    }
    __syncthreads();

    // ---- compute: thread (tx,ty) -> outputs rows 2ty..+1, cols 2tx..+1 (local) ----
    int tx = tid & 15, ty = tid >> 4;

    float acc[NORIENT][2][2];
#pragma unroll
    for (int c = 0; c < NORIENT; ++c)
#pragma unroll
        for (int dy = 0; dy < 2; ++dy) {
            acc[c][dy][0] = 0.f;
            acc[c][dy][1] = 0.f;
        }

#pragma unroll
    for (int rr = 0; rr < 7; ++rr) {
        const float* lp = &tile[(4 * ty + rr) * SROW + 4 * tx];
        float4 Ra = *(const float4*)lp;          // cols 4tx..4tx+3
        float4 Rb = *(const float4*)(lp + 4);    // cols 4tx+4..4tx+7
        float R[8] = {Ra.x, Ra.y, Ra.z, Ra.w, Rb.x, Rb.y, Rb.z, Rb.w};

#pragma unroll
        for (int dy = 0; dy < 2; ++dy) {
            int i = rr - 2 * dy;
            if (i < 0 || i > 4) continue;        // compile-time
#pragma unroll
            for (int j = 0; j < 5; ++j) {
                // wave-uniform address -> LDS broadcast, conflict-free
                const float4 w0 = *(const float4*)&wLds[(i * 5 + j) * NORIENT];
                const float4 w1 = *(const float4*)&wLds[(i * 5 + j) * NORIENT + 4];
                float wv[8] = {w0.x, w0.y, w0.z, w0.w, w1.x, w1.y, w1.z, w1.w};
#pragma unroll
                for (int c = 0; c < NORIENT; ++c) {
                    acc[c][dy][0] = fmaf(R[j],     wv[c], acc[c][dy][0]);
                    acc[c][dy][1] = fmaf(R[j + 2], wv[c], acc[c][dy][1]);
                }
            }
        }
    }

    long cs = (long)OH * OW;
    int oy = 32 * by + 2 * ty, ox = 32 * bx + 2 * tx;
    long ob0 = (long)n * NORIENT * cs + (long)oy * OW + ox;
#pragma unroll
    for (int c = 0; c < NORIENT; ++c) {
#pragma unroll
        for (int dy = 0; dy < 2; ++dy) {
            *(float2*)(out + ob0 + (long)c * cs + (long)dy * OW) =
                make_float2(acc[c][dy][0], acc[c][dy][1]);
        }
    }
}

// ---------------- forward (direct, exact R7 version) for small levels ----------------
__global__ void fwd_conv_kernel(const float* __restrict__ in, long in_img_stride,
                                const float* __restrict__ filt,
                                float* __restrict__ out,
                                int H, int W, int OH, int OW, int N) {
    int OH2 = OH >> 1, OW2 = OW >> 1;
    unsigned sb = xcd_swz(blockIdx.x, gridDim.x);
    long idx = (long)sb * blockDim.x + threadIdx.x;
    long total = (long)N * OH2 * OW2;
    if (idx >= total) return;
    int ox2 = (int)(idx % OW2);
    long t = idx / OW2;
    int oy2 = (int)(t % OH2);
    int n = (int)(t / OH2);

    const float* __restrict__ ip = in + (long)n * in_img_stride;
    int x0 = 4 * ox2;
    bool um = ox2 > 0, up = (x0 + 4) < W;
    int bA = um ? x0 - 2 : 0;
    int bD = up ? x0 + 4 : W - 1;

    float acc[NORIENT][2][2];
#pragma unroll
    for (int c = 0; c < NORIENT; ++c)
#pragma unroll
        for (int dy = 0; dy < 2; ++dy) {
            acc[c][dy][0] = 0.f;
            acc[c][dy][1] = 0.f;
        }

#pragma unroll
    for (int r = 0; r < 7; ++r) {
        int y = 4 * oy2 - 2 + r;
        bool vy = (y >= 0) & (y < H);
        int yc = vy ? y : (y < 0 ? 0 : H - 1);
        float rm = vy ? 1.f : 0.f;
        const float* __restrict__ row = ip + (long)yc * W;
        float2 A = *(const float2*)(row + bA);
        float4 B = *(const float4*)(row + x0);
        float  D = row[bD];
        float mL = um ? rm : 0.f, mR = up ? rm : 0.f;
        float P[7];
        P[0] = A.x * mL; P[1] = A.y * mL;
        P[2] = B.x * rm; P[3] = B.y * rm; P[4] = B.z * rm; P[5] = B.w * rm;
        P[6] = D * mR;

#pragma unroll
        for (int dy = 0; dy < 2; ++dy) {
            int i = r - 2 * dy;
            if (i < 0 || i > 4) continue;
#pragma unroll
            for (int j = 0; j < 5; ++j) {
#pragma unroll
                for (int c = 0; c < NORIENT; ++c) {
                    float wv = filt[c * 25 + i * 5 + j];
                    acc[c][dy][0] = fmaf(P[j],     wv, acc[c][dy][0]);
                    acc[c][dy][1] = fmaf(P[j + 2], wv, acc[c][dy][1]);
                }
            }
        }
    }

    long cs = (long)OH * OW;
    long ob0 = (long)n * NORIENT * cs + (long)(2 * oy2) * OW + 2 * ox2;
#pragma unroll
    for (int c = 0; c < NORIENT; ++c) {
#pragma unroll
        for (int dy = 0; dy < 2; ++dy) {
            *(float2*)(out + ob0 + (long)c * cs + (long)dy * OW) =
                make_float2(acc[c][dy][0], acc[c][dy][1]);
        }
    }
}

// ---------------- inverse: transposed conv, 8 -> 1 channel, stride 2 ----------------
// Exact R4/R7 version (clean counters: WRITE == output, no spill).
__global__ void inv_tconv_kernel(const float* __restrict__ rec, long rec_img_stride,
                                 const float* __restrict__ coef,
                                 const float* __restrict__ filt,
                                 float* __restrict__ out,
                                 int h, int w, int N) {
    int h2 = h >> 1, w2 = w >> 1;
    unsigned sb = xcd_swz(blockIdx.x, gridDim.x);
    long idx = (long)sb * blockDim.x + threadIdx.x;
    long total = (long)N * h2 * w2;
    if (idx >= total) return;
    int b0 = (int)(idx % w2);
    long t = idx / w2;
    int a0 = (int)(t % h2);
    int n = (int)(t / h2);

    const float* __restrict__ rp = rec + (long)n * rec_img_stride;
    const float* __restrict__ cp = coef + (long)n * (long)NORIENT * h * w;
    int cs = h * w;

    bool fmv = a0 > 0, fpv = a0 < h2 - 1;
    bool um = b0 > 0, up = b0 < w2 - 1;
    float fm = fmv ? 1.f : 0.f, fp_ = fpv ? 1.f : 0.f;
    int r0 = (fmv ? 2 * a0 - 1 : 0) * w;
    int r1 = (2 * a0) * w;
    int r2 = (2 * a0 + 1) * w;
    int r3 = (fpv ? 2 * a0 + 2 : 2 * a0 + 1) * w;
    int cL = um ? 2 * b0 - 2 : 0;
    int cM = 2 * b0;
    int cR = up ? 2 * b0 + 2 : 0;

    float acc[2][2][2][2];  // [sr][sc][dy][dx]
#pragma unroll
    for (int i = 0; i < 2; ++i)
#pragma unroll
        for (int j = 0; j < 2; ++j)
#pragma unroll
            for (int k = 0; k < 2; ++k)
#pragma unroll
                for (int l = 0; l < 2; ++l) acc[i][j][k][l] = 0.f;

    auto do_channel = [&](const float* __restrict__ src, const float* __restrict__ F) {
        float P[4][4];
        const int ro[4] = {r0, r1, r2, r3};
        const float rm[4] = {fm, 1.f, 1.f, fp_};
#pragma unroll
        for (int r = 0; r < 4; ++r) {
            const float* base = src + ro[r];
            float2 L = *(const float2*)(base + cL);
            float2 M = *(const float2*)(base + cM);
            float2 R = *(const float2*)(base + cR);
            float mask = rm[r];
            P[r][0] = (um ? L.y : 0.f) * mask;
            P[r][1] = M.x * mask;
            P[r][2] = M.y * mask;
            P[r][3] = (up ? R.x : 0.f) * mask;
        }
#pragma unroll
        for (int a = 0; a < 3; ++a) {
#pragma unroll
            for (int b = 0; b < 3; ++b) {
                float w00 = F[(4 - 2 * a) * 5 + (4 - 2 * b)];
                float w01 = (b >= 1) ? F[(4 - 2 * a) * 5 + (5 - 2 * b)] : 0.f;
                float w10 = (a >= 1) ? F[(5 - 2 * a) * 5 + (4 - 2 * b)] : 0.f;
                float w11 = (a >= 1 && b >= 1) ? F[(5 - 2 * a) * 5 + (5 - 2 * b)] : 0.f;
#pragma unroll
                for (int sr = 0; sr < 2; ++sr) {
#pragma unroll
                    for (int sc = 0; sc < 2; ++sc) {
                        float pv = P[sr + a][sc + b];
                        acc[sr][sc][0][0] = fmaf(pv, w00, acc[sr][sc][0][0]);
                        if (b >= 1) acc[sr][sc][0][1] = fmaf(pv, w01, acc[sr][sc][0][1]);
                        if (a >= 1) acc[sr][sc][1][0] = fmaf(pv, w10, acc[sr][sc][1][0]);
                        if (a >= 1 && b >= 1)
                                    acc[sr][sc][1][1] = fmaf(pv, w11, acc[sr][sc][1][1]);
                    }
                }
            }
        }
    };

    do_channel(rp, filt);
#pragma unroll
    for (int c = 1; c < NORIENT; ++c)
        do_channel(cp + (long)c * cs, filt + c * 25);

    int OW = w << 1;
    long ob = (long)n * 4 * (long)cs + (long)(4 * a0) * OW + 4 * b0;
    *(float4*)(out + ob)          = make_float4(acc[0][0][0][0], acc[0][0][0][1],
                                                acc[0][1][0][0], acc[0][1][0][1]);
    *(float4*)(out + ob + OW)     = make_float4(acc[0][0][1][0], acc[0][0][1][1],
                                                acc[0][1][1][0], acc[0][1][1][1]);
    *(float4*)(out + ob + 2 * OW) = make_float4(acc[1][0][0][0], acc[1][0][0][1],
                                                acc[1][1][0][0], acc[1][1][0][1]);
    *(float4*)(out + ob + 3 * OW) = make_float4(acc[1][0][1][0], acc[1][0][1][1],
                                                acc[1][1][1][0], acc[1][1][1][1]);
}

extern "C" void kernel_launch(void* const* d_in, const int* in_sizes, int n_in,
                              void* d_out, int out_size, void* d_ws, size_t ws_size,
                              hipStream_t stream) {
    const float* x     = (const float*)d_in[0];
    const float* fwd_f = (const float*)d_in[1];
    const float* inv_f = (const float*)d_in[2];
    float* out = (float*)d_out;
    float* ws  = (float*)d_ws;

    const int N = 32;

    // workspace layout (floats) — all offsets multiples of 4 -> 16B aligned
    float* l4 = ws;                  // 32*8*256*256 = 16,777,216
    float* l3 = l4 + 16777216;       // 32*8*128*128 =  4,194,304
    float* l2 = l3 + 4194304;        // 32*8*64*64   =  1,048,576
    float* l1 = l2 + 1048576;        // 32*8*32*32   =    262,144
    float* r1 = l1 + 262144;         // 32*64*64     =    131,072
    float* r2 = r1 + 131072;         // 32*128*128   =    524,288
    float* r3 = r2 + 524288;         // 32*256*256   =  2,097,152

    dim3 blk(256);
    auto nblocks = [](long total) { return dim3((unsigned)((total + 255) / 256)); };

    // ---- forward transform ----
    // levels 1-2: LDS-tiled (grid = N * OH/32 * OW/32 blocks)
    fwd_conv_lds_kernel<<<dim3(32 * 8 * 8), blk, 0, stream>>>(
        x, 512L * 512, fwd_f, l4, 512, 512, 256, 256, N);
    fwd_conv_lds_kernel<<<dim3(32 * 4 * 4), blk, 0, stream>>>(
        l4, 8L * 256 * 256, fwd_f, l3, 256, 256, 128, 128, N);
    // levels 3-4: direct (tiny)
    fwd_conv_kernel<<<nblocks(32L * 32 * 32), blk, 0, stream>>>(
        l3, 8L * 128 * 128, fwd_f, l2, 128, 128, 64, 64, N);
    fwd_conv_kernel<<<nblocks(32L * 16 * 16), blk, 0, stream>>>(
        l2, 8L * 64 * 64, fwd_f, l1, 64, 64, 32, 32, N);

    // ---- inverse transform (threads = N * h/2 * w/2) ----
    inv_tconv_kernel<<<nblocks(32L * 16 * 16), blk, 0, stream>>>(
        l1, 8L * 32 * 32, l1, inv_f, r1, 32, 32, N);
    inv_tconv_kernel<<<nblocks(32L * 32 * 32), blk, 0, stream>>>(
        r1, 64L * 64, l2, inv_f, r2, 64, 64, N);
    inv_tconv_kernel<<<nblocks(32L * 64 * 64), blk, 0, stream>>>(
        r2, 128L * 128, l3, inv_f, r3, 128, 128, N);
    inv_tconv_kernel<<<nblocks(32L * 128 * 128), blk, 0, stream>>>(
        r3, 256L * 256, l4, inv_f, out, 256, 256, N);
}

// Round 12
// 96.529 us; speedup vs baseline: 3.0639x; 3.0639x over previous
//
#include <hip/hip_runtime.h>

#define NORIENT 8

// XCD-aware block swizzle: dispatch d -> XCD d%8 (round-robin). Remap so each
// XCD gets a contiguous chunk of logical tiles (halo rows shared in its L2).
__device__ __forceinline__ unsigned xcd_swz(unsigned bid, unsigned nwg) {
    unsigned chunk = nwg >> 3;
    return (nwg & 7u) ? bid : (bid & 7u) * chunk + (bid >> 3);
}

// -------- forward, wave-per-channel: stride-2 5x5 conv, 1 -> 8 ch --------
// Block = 512 threads = 8 waves; wave w computes channel w only -> its 25
// weights are hoisted into SGPRs ONCE (readfirstlane-uniform base), so the
// 800-FMA body has ZERO scalar/global loads (R9-R11 lesson: in-body weight
// s_loads serialize with ds_reads on the shared lgkmcnt; VGPR-array fixes
// spill past the 64-VGPR wall).
// Output tile 32x32; lane (lx,ly) -> 4x4 outputs at (4ly,4lx) of channel w.
// LDS tile: input rows 64by-2..+64 (67), cols 64bx-4..+67 (72), layout
// col c -> offset c + 4*(c>>3) (SROW=104): lane stride 12 floats = 48B
// spreads over all 32 banks (2-way aliasing = free; naive 32B stride = 4-way).
__global__ void fwd_conv_wave_kernel(const float* __restrict__ in, long in_img_stride,
                                     const float* __restrict__ filt,
                                     float* __restrict__ out,
                                     int H, int W, int OH, int OW, int N) {
    constexpr int SROW = 104;
    __shared__ float tile[67 * SROW];      // 27,872 B

    int nbx = OW >> 5, nby = OH >> 5;
    unsigned sb = xcd_swz(blockIdx.x, gridDim.x);
    int bx = (int)(sb % nbx);
    unsigned t = sb / nbx;
    int by = (int)(t % nby);
    int n = (int)(t / nby);

    const float* __restrict__ ip = in + (long)n * in_img_stride;
    int tid = threadIdx.x;

    // ---- hoist this wave's 25 weights (uniform -> SGPRs) ----
    int w = __builtin_amdgcn_readfirstlane(tid >> 6);
    const float* __restrict__ F = filt + w * 25;
    float Wt[25];
#pragma unroll
    for (int k = 0; k < 25; ++k) Wt[k] = F[k];

    // ---- stage 67 rows x 18 float4 (gy from 64by-2, gx from 64bx-4) ----
    // Border float4s are fully valid or fully invalid (W % 4 == 0).
    int gy0 = 64 * by - 2, gx0 = 64 * bx - 4;
#pragma unroll
    for (int k = 0; k < 3; ++k) {
        int e = tid + k * 512;
        if (e < 67 * 18) {
            int row = e / 18, m = e - row * 18;
            int gy = gy0 + row, gx = gx0 + 4 * m;
            bool vl = (gy >= 0) & (gy < H) & (gx >= 0) & (gx <= W - 4);
            float4 val = *(const float4*)(ip + (vl ? ((long)gy * W + gx) : 0));
            float msk = vl ? 1.f : 0.f;
            int off = row * SROW + 4 * m + 4 * (m >> 1);   // c=4m -> c+4*(c>>3)
            *(float4*)&tile[off] = make_float4(val.x * msk, val.y * msk,
                                               val.z * msk, val.w * msk);
        }
    }
    __syncthreads();

    // ---- compute: lane -> 4x4 outputs of channel w ----
    int lane = tid & 63;
    int lx = lane & 7, ly = lane >> 3;

    float acc[4][4];
#pragma unroll
    for (int o = 0; o < 4; ++o)
#pragma unroll
        for (int dx = 0; dx < 4; ++dx) acc[o][dx] = 0.f;

#pragma unroll
    for (int r = 0; r < 11; ++r) {
        // input row 8ly-2+r (tile row 8ly+r); needed cols c = 8lx+2 .. 8lx+14
        // (tile-col c maps gx = 64bx-4+c). Swizzled offsets: base 12lx, reads
        // at +0 (c 8lx..+3), +4 (c +4..7), +12 (c +8..11), +16 (c +12..15).
        int base = (8 * ly + r) * SROW + 12 * lx;
        float4 A = *(const float4*)&tile[base];
        float4 B = *(const float4*)&tile[base + 4];
        float4 C = *(const float4*)&tile[base + 12];
        float4 Dd = *(const float4*)&tile[base + 16];
        float P[16] = {A.x, A.y, A.z, A.w, B.x, B.y, B.z, B.w,
                       C.x, C.y, C.z, C.w, Dd.x, Dd.y, Dd.z, Dd.w};

#pragma unroll
        for (int o = 0; o < 4; ++o) {
            int i = r - 2 * o;
            if (i < 0 || i > 4) continue;        // compile-time
#pragma unroll
            for (int j = 0; j < 5; ++j) {
                float wv = Wt[i * 5 + j];
#pragma unroll
                for (int dx = 0; dx < 4; ++dx)
                    acc[o][dx] = fmaf(P[2 + 2 * dx + j], wv, acc[o][dx]);
            }
        }
    }

    long cs = (long)OH * OW;
    int oy = 32 * by + 4 * ly, ox = 32 * bx + 4 * lx;
    long ob = ((long)n * NORIENT + w) * cs + (long)oy * OW + ox;
#pragma unroll
    for (int o = 0; o < 4; ++o)
        *(float4*)(out + ob + (long)o * OW) =
            make_float4(acc[o][0], acc[o][1], acc[o][2], acc[o][3]);
}

// ---------------- inverse: transposed conv, 8 -> 1 channel, stride 2 ----------------
// Exact R4/R7 version (clean counters: WRITE == output, no spill).
__global__ void inv_tconv_kernel(const float* __restrict__ rec, long rec_img_stride,
                                 const float* __restrict__ coef,
                                 const float* __restrict__ filt,
                                 float* __restrict__ out,
                                 int h, int w, int N) {
    int h2 = h >> 1, w2 = w >> 1;
    unsigned sb = xcd_swz(blockIdx.x, gridDim.x);
    long idx = (long)sb * blockDim.x + threadIdx.x;
    long total = (long)N * h2 * w2;
    if (idx >= total) return;
    int b0 = (int)(idx % w2);
    long t = idx / w2;
    int a0 = (int)(t % h2);
    int n = (int)(t / h2);

    const float* __restrict__ rp = rec + (long)n * rec_img_stride;
    const float* __restrict__ cp = coef + (long)n * (long)NORIENT * h * w;
    int cs = h * w;

    bool fmv = a0 > 0, fpv = a0 < h2 - 1;
    bool um = b0 > 0, up = b0 < w2 - 1;
    float fm = fmv ? 1.f : 0.f, fp_ = fpv ? 1.f : 0.f;
    int r0 = (fmv ? 2 * a0 - 1 : 0) * w;
    int r1 = (2 * a0) * w;
    int r2 = (2 * a0 + 1) * w;
    int r3 = (fpv ? 2 * a0 + 2 : 2 * a0 + 1) * w;
    int cL = um ? 2 * b0 - 2 : 0;
    int cM = 2 * b0;
    int cR = up ? 2 * b0 + 2 : 0;

    float acc[2][2][2][2];  // [sr][sc][dy][dx]
#pragma unroll
    for (int i = 0; i < 2; ++i)
#pragma unroll
        for (int j = 0; j < 2; ++j)
#pragma unroll
            for (int k = 0; k < 2; ++k)
#pragma unroll
                for (int l = 0; l < 2; ++l) acc[i][j][k][l] = 0.f;

    auto do_channel = [&](const float* __restrict__ src, const float* __restrict__ F) {
        float P[4][4];
        const int ro[4] = {r0, r1, r2, r3};
        const float rm[4] = {fm, 1.f, 1.f, fp_};
#pragma unroll
        for (int r = 0; r < 4; ++r) {
            const float* base = src + ro[r];
            float2 L = *(const float2*)(base + cL);
            float2 M = *(const float2*)(base + cM);
            float2 R = *(const float2*)(base + cR);
            float mask = rm[r];
            P[r][0] = (um ? L.y : 0.f) * mask;
            P[r][1] = M.x * mask;
            P[r][2] = M.y * mask;
            P[r][3] = (up ? R.x : 0.f) * mask;
        }
#pragma unroll
        for (int a = 0; a < 3; ++a) {
#pragma unroll
            for (int b = 0; b < 3; ++b) {
                float w00 = F[(4 - 2 * a) * 5 + (4 - 2 * b)];
                float w01 = (b >= 1) ? F[(4 - 2 * a) * 5 + (5 - 2 * b)] : 0.f;
                float w10 = (a >= 1) ? F[(5 - 2 * a) * 5 + (4 - 2 * b)] : 0.f;
                float w11 = (a >= 1 && b >= 1) ? F[(5 - 2 * a) * 5 + (5 - 2 * b)] : 0.f;
#pragma unroll
                for (int sr = 0; sr < 2; ++sr) {
#pragma unroll
                    for (int sc = 0; sc < 2; ++sc) {
                        float pv = P[sr + a][sc + b];
                        acc[sr][sc][0][0] = fmaf(pv, w00, acc[sr][sc][0][0]);
                        if (b >= 1) acc[sr][sc][0][1] = fmaf(pv, w01, acc[sr][sc][0][1]);
                        if (a >= 1) acc[sr][sc][1][0] = fmaf(pv, w10, acc[sr][sc][1][0]);
                        if (a >= 1 && b >= 1)
                                    acc[sr][sc][1][1] = fmaf(pv, w11, acc[sr][sc][1][1]);
                    }
                }
            }
        }
    };

    do_channel(rp, filt);
#pragma unroll
    for (int c = 1; c < NORIENT; ++c)
        do_channel(cp + (long)c * cs, filt + c * 25);

    int OW = w << 1;
    long ob = (long)n * 4 * (long)cs + (long)(4 * a0) * OW + 4 * b0;
    *(float4*)(out + ob)          = make_float4(acc[0][0][0][0], acc[0][0][0][1],
                                                acc[0][1][0][0], acc[0][1][0][1]);
    *(float4*)(out + ob + OW)     = make_float4(acc[0][0][1][0], acc[0][0][1][1],
                                                acc[0][1][1][0], acc[0][1][1][1]);
    *(float4*)(out + ob + 2 * OW) = make_float4(acc[1][0][0][0], acc[1][0][0][1],
                                                acc[1][1][0][0], acc[1][1][0][1]);
    *(float4*)(out + ob + 3 * OW) = make_float4(acc[1][0][1][0], acc[1][0][1][1],
                                                acc[1][1][1][0], acc[1][1][1][1]);
}

extern "C" void kernel_launch(void* const* d_in, const int* in_sizes, int n_in,
                              void* d_out, int out_size, void* d_ws, size_t ws_size,
                              hipStream_t stream) {
    const float* x     = (const float*)d_in[0];
    const float* fwd_f = (const float*)d_in[1];
    const float* inv_f = (const float*)d_in[2];
    float* out = (float*)d_out;
    float* ws  = (float*)d_ws;

    const int N = 32;

    // workspace layout (floats) — all offsets multiples of 4 -> 16B aligned
    float* l4 = ws;                  // 32*8*256*256 = 16,777,216
    float* l3 = l4 + 16777216;       // 32*8*128*128 =  4,194,304
    float* l2 = l3 + 4194304;        // 32*8*64*64   =  1,048,576
    float* l1 = l2 + 1048576;        // 32*8*32*32   =    262,144
    float* r1 = l1 + 262144;         // 32*64*64     =    131,072
    float* r2 = r1 + 131072;         // 32*128*128   =    524,288
    float* r3 = r2 + 524288;         // 32*256*256   =  2,097,152

    dim3 blkF(512), blk(256);
    auto nblocks = [](long total) { return dim3((unsigned)((total + 255) / 256)); };

    // ---- forward transform: wave-per-channel, grid = N * (OH/32) * (OW/32) ----
    fwd_conv_wave_kernel<<<dim3(32 * 8 * 8), blkF, 0, stream>>>(
        x, 512L * 512, fwd_f, l4, 512, 512, 256, 256, N);
    fwd_conv_wave_kernel<<<dim3(32 * 4 * 4), blkF, 0, stream>>>(
        l4, 8L * 256 * 256, fwd_f, l3, 256, 256, 128, 128, N);
    fwd_conv_wave_kernel<<<dim3(32 * 2 * 2), blkF, 0, stream>>>(
        l3, 8L * 128 * 128, fwd_f, l2, 128, 128, 64, 64, N);
    fwd_conv_wave_kernel<<<dim3(32 * 1 * 1), blkF, 0, stream>>>(
        l2, 8L * 64 * 64, fwd_f, l1, 64, 64, 32, 32, N);

    // ---- inverse transform (threads = N * h/2 * w/2) ----
    inv_tconv_kernel<<<nblocks(32L * 16 * 16), blk, 0, stream>>>(
        l1, 8L * 32 * 32, l1, inv_f, r1, 32, 32, N);
    inv_tconv_kernel<<<nblocks(32L * 32 * 32), blk, 0, stream>>>(
        r1, 64L * 64, l2, inv_f, r2, 64, 64, N);
    inv_tconv_kernel<<<nblocks(32L * 64 * 64), blk, 0, stream>>>(
        r2, 128L * 128, l3, inv_f, r3, 128, 128, N);
    inv_tconv_kernel<<<nblocks(32L * 128 * 128), blk, 0, stream>>>(
        r3, 256L * 256, l4, inv_f, out, 256, 256, N);
}